// Round 3
// baseline (729.092 us; speedup 1.0000x reference)
//
#include <hip/hip_runtime.h>
#include <hip/hip_bf16.h>
#include <stdint.h>

#define T_TOK 2048
#define H_DIM 2048
#define S_SEQ 1024
#define NE_ROUTED 8
#define NE 9
#define IMOE 1408
#define ISHARED 5632
#define UNCOND_LBL 1000

typedef short bf16x8 __attribute__((ext_vector_type(8)));
typedef float f32x4 __attribute__((ext_vector_type(4)));

__device__ __forceinline__ unsigned short f2bf(float f) {
  union { float f; unsigned int u; } v; v.f = f;
  unsigned int u = v.u;
  return (unsigned short)((u + 0x7fffu + ((u >> 16) & 1u)) >> 16);
}

// async global->LDS, 16 B per lane; lds dest must be wave-uniform base
__device__ __forceinline__ void gl16(const void* g, void* l) {
  __builtin_amdgcn_global_load_lds(
      (const __attribute__((address_space(1))) unsigned int*)g,
      (__attribute__((address_space(3))) unsigned int*)l, 16, 0, 0);
}

// ---------------- convert x (f32) -> bf16 ----------------
__global__ __launch_bounds__(256) void cvt_bf16_kernel(const float* __restrict__ in,
                                                       unsigned short* __restrict__ out,
                                                       int n) {
  int i = (blockIdx.x * 256 + threadIdx.x) * 4;
  if (i >= n) return;
  float4 v = *(const float4*)(in + i);
  uint2 p;
  p.x = (unsigned)f2bf(v.x) | ((unsigned)f2bf(v.y) << 16);
  p.y = (unsigned)f2bf(v.z) | ((unsigned)f2bf(v.w) << 16);
  *(uint2*)(out + i) = p;
}

// ---------------- router: one wave per token ----------------
__global__ __launch_bounds__(256) void router_kernel(
    const float* __restrict__ x, const int* __restrict__ labels,
    const float* __restrict__ cc,
    int* __restrict__ counts, int* __restrict__ toklist, float* __restrict__ wts) {
  int t = (int)((blockIdx.x * 256 + threadIdx.x) >> 6);
  int lane = threadIdx.x & 63;
  if (t >= T_TOK) return;
  const float* xp = x + (size_t)t * H_DIM;
  float xx = 0.f;
  float d[NE_ROUTED], cn[NE_ROUTED];
#pragma unroll
  for (int e = 0; e < NE_ROUTED; e++) { d[e] = 0.f; cn[e] = 0.f; }
  for (int h = lane; h < H_DIM; h += 64) {
    float xv = xp[h];
    xx += xv * xv;
#pragma unroll
    for (int e = 0; e < NE_ROUTED; e++) {
      float cv = cc[e * H_DIM + h];
      d[e] += xv * cv;
      cn[e] += cv * cv;
    }
  }
#pragma unroll
  for (int off = 32; off > 0; off >>= 1) {
    xx += __shfl_xor(xx, off);
#pragma unroll
    for (int e = 0; e < NE_ROUTED; e++) {
      d[e] += __shfl_xor(d[e], off);
      cn[e] += __shfl_xor(cn[e], off);
    }
  }
  if (lane == 0) {
    int lab = labels[t / S_SEQ];
    if (lab == UNCOND_LBL) {
      int r = atomicAdd(&counts[NE - 1], 1);
      toklist[(NE - 1) * T_TOK + r] = t;
      wts[(NE - 1) * T_TOK + r] = 1.0f;
    } else {
      float xn = sqrtf(xx + 1e-12f);
      float cosv[NE_ROUTED];
      float mx = -1e30f;
#pragma unroll
      for (int e = 0; e < NE_ROUTED; e++) {
        cosv[e] = d[e] / (xn * sqrtf(cn[e] + 1e-12f));
        mx = fmaxf(mx, cosv[e]);
      }
      float p[NE_ROUTED];
      float s = 0.f;
#pragma unroll
      for (int e = 0; e < NE_ROUTED; e++) { p[e] = __expf(cosv[e] - mx); s += p[e]; }
      int i1 = 0;
#pragma unroll
      for (int e = 1; e < NE_ROUTED; e++) if (p[e] > p[i1]) i1 = e;
      int i2 = (i1 == 0) ? 1 : 0;
#pragma unroll
      for (int e = 0; e < NE_ROUTED; e++) if (e != i2 && e != i1 && p[e] > p[i2]) i2 = e;
      int r1 = atomicAdd(&counts[i1], 1);
      toklist[i1 * T_TOK + r1] = t;
      wts[i1 * T_TOK + r1] = p[i1] / s;
      int r2 = atomicAdd(&counts[i2], 1);
      toklist[i2 * T_TOK + r2] = t;
      wts[i2 * T_TOK + r2] = p[i2] / s;
    }
  }
}

// ============================================================================
// FAST PATH
// Striped-swizzled bf16 layout: tensor[e][ns][kt][u][8] where ns=n/16, kt=k/32,
// logical unit ul = (n&15)*4 + ((k>>3)&3), physical u = ul ^ ((ul>>3)&7).
// ============================================================================

// Transpose+convert W[e][K][N] f32 -> striped W'[e][N/16][K/32][512] bf16.
__global__ __launch_bounds__(256) void transpose_cvt(
    const float* __restrict__ src, unsigned short* __restrict__ dst, int K, int N) {
  int e = blockIdx.z;
  int kt = blockIdx.y;          // 32 k rows
  int n0 = blockIdx.x << 6;     // 64 n cols = 4 stripes
  int NS = N >> 4, KT = K >> 5;
  const float* sp0 = src + (size_t)e * K * N + (size_t)kt * 32 * N + n0;
  __shared__ float tile[32][72];
  int t = threadIdx.x;
  int kr = t >> 3, nc = (t & 7) << 3;
  const float* sp = sp0 + (size_t)kr * N + nc;
  float4 a = *(const float4*)sp;
  float4 b = *(const float4*)(sp + 4);
  *(float4*)&tile[kr][nc] = a;
  *(float4*)&tile[kr][nc + 4] = b;
  __syncthreads();
  int nsl = t >> 6, up = t & 63;
  int ul = up ^ ((up >> 3) & 7);
  int rn = ul >> 2, fq = ul & 3;
  int nl = (nsl << 4) + rn;
  unsigned int pk[4];
#pragma unroll
  for (int j = 0; j < 4; j++) {
    float f0 = tile[fq * 8 + 2 * j][nl];
    float f1 = tile[fq * 8 + 2 * j + 1][nl];
    pk[j] = (unsigned)f2bf(f0) | ((unsigned)f2bf(f1) << 16);
  }
  size_t ns = (size_t)e * NS + (n0 >> 4) + nsl;
  unsigned short* dp = dst + (ns * KT + kt) * 512 + up * 8;
  *(uint4*)dp = make_uint4(pk[0], pk[1], pk[2], pk[3]);
}

// Fused gate+up GEMM, striped-B, global_load_lds, 3-deep counted-vmcnt pipeline.
template <bool ROUTED>
__global__ __launch_bounds__(256) void gemm_up2(
    const unsigned short* __restrict__ X,     // [T][K] bf16 (row-major)
    const unsigned short* __restrict__ WgT,   // striped
    const unsigned short* __restrict__ WuT,   // striped
    unsigned short* __restrict__ Hout,        // striped [e][T/16][N/32][512]
    const int* __restrict__ toklist, const int* __restrict__ counts,
    int K, int N) {
  int e = ROUTED ? blockIdx.z : 0;
  int m0 = blockIdx.y * 128;
  int n0 = blockIdx.x * 128;
  int cnt = ROUTED ? counts[e] : T_TOK;
  if (m0 >= cnt) return;
  int KT = K >> 5;
  int NS = N >> 4;
  int MS = T_TOK >> 4;
  int KTO = N >> 5;

  __shared__ unsigned short As[3][4096];
  __shared__ unsigned short Bgs[3][4096];
  __shared__ unsigned short Bus[3][4096];

  int tid = threadIdx.x, lane = tid & 63, wid = tid >> 6;
  int wr = wid >> 1, wc = wid & 1;
  int fr = lane & 15, fq = lane >> 4;

  // per-lane swizzled A gather source
  int v = lane ^ ((lane >> 3) & 7);
  const unsigned short* aptr[2];
#pragma unroll
  for (int i = 0; i < 2; i++) {
    int r = m0 + wid * 32 + i * 16 + (v >> 2);
    if (r >= cnt) r = cnt - 1;
    int tok = ROUTED ? toklist[e * T_TOK + r] : r;
    aptr[i] = X + (size_t)tok * K + ((v & 3) << 3);
  }
  const unsigned short *bgp[2], *bup[2];
#pragma unroll
  for (int i = 0; i < 2; i++) {
    size_t ns = (size_t)e * NS + (n0 >> 4) + wid * 2 + i;
    bgp[i] = WgT + ns * KT * 512 + lane * 8;
    bup[i] = WuT + ns * KT * 512 + lane * 8;
  }
  int fo = fr * 4 + fq;
  fo = (fo ^ ((fo >> 3) & 7)) * 8;

  f32x4 zero = {0.f, 0.f, 0.f, 0.f};
  f32x4 accg[4][4], accu[4][4];
#pragma unroll
  for (int i = 0; i < 4; i++)
#pragma unroll
    for (int j = 0; j < 4; j++) { accg[i][j] = zero; accu[i][j] = zero; }

  auto stage = [&](int b, int kt) {
#pragma unroll
    for (int i = 0; i < 2; i++) {
      gl16(aptr[i] + (size_t)kt * 32, &As[b][(wid * 2 + i) * 512]);
      gl16(bgp[i] + (size_t)kt * 512, &Bgs[b][(wid * 2 + i) * 512]);
      gl16(bup[i] + (size_t)kt * 512, &Bus[b][(wid * 2 + i) * 512]);
    }
  };

  // prologue: 2 tiles in flight (6 loads/thread each)
  stage(0, 0);
  if (KT > 1) stage(1, 1);
  int b = 0;
  for (int kt = 0; kt < KT; ++kt) {
    if (kt + 2 < KT) {
      int nb = b + 2; if (nb >= 3) nb -= 3;
      stage(nb, kt + 2);
      asm volatile("s_waitcnt vmcnt(12)" ::: "memory");   // tile kt landed
    } else if (kt + 1 < KT) {
      asm volatile("s_waitcnt vmcnt(6)" ::: "memory");
    } else {
      asm volatile("s_waitcnt vmcnt(0)" ::: "memory");
    }
    __builtin_amdgcn_s_barrier();
    __builtin_amdgcn_sched_barrier(0);
    bf16x8 af[4], bgf[4], bff[4];
#pragma unroll
    for (int mi = 0; mi < 4; mi++)
      af[mi] = *(const bf16x8*)&As[b][(wr * 4 + mi) * 512 + fo];
#pragma unroll
    for (int ni = 0; ni < 4; ni++) {
      bgf[ni] = *(const bf16x8*)&Bgs[b][(wc * 4 + ni) * 512 + fo];
      bff[ni] = *(const bf16x8*)&Bus[b][(wc * 4 + ni) * 512 + fo];
    }
    asm volatile("s_waitcnt lgkmcnt(0)" ::: "memory");
    __builtin_amdgcn_sched_barrier(0);
    __builtin_amdgcn_s_setprio(1);
#pragma unroll
    for (int mi = 0; mi < 4; mi++)
#pragma unroll
      for (int ni = 0; ni < 4; ni++) {
        accg[mi][ni] = __builtin_amdgcn_mfma_f32_16x16x32_bf16(af[mi], bgf[ni], accg[mi][ni], 0, 0, 0);
        accu[mi][ni] = __builtin_amdgcn_mfma_f32_16x16x32_bf16(af[mi], bff[ni], accu[mi][ni], 0, 0, 0);
      }
    __builtin_amdgcn_s_setprio(0);
    __builtin_amdgcn_sched_barrier(0);
    __builtin_amdgcn_s_barrier();
    ++b; if (b >= 3) b -= 3;
  }

  // epilogue: silu(g)*u -> bf16, write striped Hout
  size_t hb = (size_t)e * MS;
#pragma unroll
  for (int mi = 0; mi < 4; mi++) {
    int rb = m0 + wr * 64 + mi * 16;
    if (rb >= cnt) continue;
    int ms = rb >> 4;
#pragma unroll
    for (int ni = 0; ni < 4; ni++) {
      int col = n0 + wc * 64 + ni * 16 + fr;
      int kto = col >> 5;
      int c3 = (col >> 3) & 3;
      int j = col & 7;
      size_t base = ((hb + ms) * (size_t)KTO + kto) * 512 + j;
#pragma unroll
      for (int jj = 0; jj < 4; jj++) {
        int row = rb + fq * 4 + jj;
        if (row < cnt) {
          float g = accg[mi][ni][jj];
          float u = accu[mi][ni][jj];
          float h = g / (1.f + __expf(-g)) * u;
          int ul = (fq * 4 + jj) * 4 + c3;
          int ph = ul ^ ((ul >> 3) & 7);
          Hout[base + ph * 8] = f2bf(h);
        }
      }
    }
  }
}

// Down GEMM: A = striped Hin, B = striped Wd; 3-deep counted-vmcnt pipeline.
template <bool ROUTED>
__global__ __launch_bounds__(256) void gemm_down2(
    const unsigned short* __restrict__ HinT,  // striped [e][T/16][K/32][512]
    const unsigned short* __restrict__ WdT,   // striped
    float* __restrict__ Out,
    const int* __restrict__ toklist, const float* __restrict__ wts,
    const int* __restrict__ counts, int K, int N) {
  int e = ROUTED ? blockIdx.z : 0;
  int m0 = blockIdx.y * 128;
  int n0 = blockIdx.x * 128;
  int cnt = ROUTED ? counts[e] : T_TOK;
  if (m0 >= cnt) return;
  int KT = K >> 5;
  int NS = N >> 4;
  int MS = T_TOK >> 4;

  __shared__ unsigned short As[3][4096];
  __shared__ unsigned short Bs[3][4096];

  int tid = threadIdx.x, lane = tid & 63, wid = tid >> 6;
  int wr = wid >> 1, wc = wid & 1;
  int fr = lane & 15, fq = lane >> 4;

  const unsigned short *ap[2], *bp[2];
#pragma unroll
  for (int i = 0; i < 2; i++) {
    size_t ms = (size_t)e * MS + (m0 >> 4) + wid * 2 + i;
    ap[i] = HinT + ms * KT * 512 + lane * 8;
    size_t ns = (size_t)e * NS + (n0 >> 4) + wid * 2 + i;
    bp[i] = WdT + ns * KT * 512 + lane * 8;
  }
  int fo = fr * 4 + fq;
  fo = (fo ^ ((fo >> 3) & 7)) * 8;

  f32x4 zero = {0.f, 0.f, 0.f, 0.f};
  f32x4 acc[4][4];
#pragma unroll
  for (int i = 0; i < 4; i++)
#pragma unroll
    for (int j = 0; j < 4; j++) acc[i][j] = zero;

  auto stage = [&](int b, int kt) {
#pragma unroll
    for (int i = 0; i < 2; i++) {
      gl16(ap[i] + (size_t)kt * 512, &As[b][(wid * 2 + i) * 512]);
      gl16(bp[i] + (size_t)kt * 512, &Bs[b][(wid * 2 + i) * 512]);
    }
  };

  stage(0, 0);
  if (KT > 1) stage(1, 1);
  int b = 0;
  for (int kt = 0; kt < KT; ++kt) {
    if (kt + 2 < KT) {
      int nb = b + 2; if (nb >= 3) nb -= 3;
      stage(nb, kt + 2);
      asm volatile("s_waitcnt vmcnt(8)" ::: "memory");
    } else if (kt + 1 < KT) {
      asm volatile("s_waitcnt vmcnt(4)" ::: "memory");
    } else {
      asm volatile("s_waitcnt vmcnt(0)" ::: "memory");
    }
    __builtin_amdgcn_s_barrier();
    __builtin_amdgcn_sched_barrier(0);
    bf16x8 af[4], bf[4];
#pragma unroll
    for (int mi = 0; mi < 4; mi++)
      af[mi] = *(const bf16x8*)&As[b][(wr * 4 + mi) * 512 + fo];
#pragma unroll
    for (int ni = 0; ni < 4; ni++)
      bf[ni] = *(const bf16x8*)&Bs[b][(wc * 4 + ni) * 512 + fo];
    asm volatile("s_waitcnt lgkmcnt(0)" ::: "memory");
    __builtin_amdgcn_sched_barrier(0);
    __builtin_amdgcn_s_setprio(1);
#pragma unroll
    for (int mi = 0; mi < 4; mi++)
#pragma unroll
      for (int ni = 0; ni < 4; ni++)
        acc[mi][ni] = __builtin_amdgcn_mfma_f32_16x16x32_bf16(af[mi], bf[ni], acc[mi][ni], 0, 0, 0);
    __builtin_amdgcn_s_setprio(0);
    __builtin_amdgcn_sched_barrier(0);
    __builtin_amdgcn_s_barrier();
    ++b; if (b >= 3) b -= 3;
  }

  int rbase = m0 + wr * 64;
  int cbase = n0 + wc * 64;
#pragma unroll
  for (int mi = 0; mi < 4; mi++)
#pragma unroll
    for (int ni = 0; ni < 4; ni++) {
      int col = cbase + ni * 16 + fr;
#pragma unroll
      for (int jj = 0; jj < 4; jj++) {
        int row = rbase + mi * 16 + fq * 4 + jj;
        if (row < cnt) {
          float vv = acc[mi][ni][jj];
          if (ROUTED) {
            int tk = toklist[e * T_TOK + row];
            float wgt = wts[e * T_TOK + row];
            atomicAdd(&Out[(size_t)tk * N + col], wgt * vv);
          } else {
            Out[(size_t)row * N + col] = vv;
          }
        }
      }
    }
}

// ============================================================================
// FALLBACK PATH (round-1 kernels) — used only if ws_size too small.
// ============================================================================
template <bool ROUTED>
__global__ __launch_bounds__(256) void gemm_up(
    const unsigned short* __restrict__ X,
    const float* __restrict__ WgAll, const float* __restrict__ WuAll,
    unsigned short* __restrict__ Hout,
    const int* __restrict__ toklist, const int* __restrict__ counts,
    int K, int N) {
  int e = blockIdx.z;
  int m0 = blockIdx.y * 128;
  int n0 = blockIdx.x * 128;
  int cnt = ROUTED ? counts[e] : T_TOK;
  if (m0 >= cnt) return;
  const float* Bg = WgAll + (size_t)e * K * N;
  const float* Bu = WuAll + (size_t)e * K * N;
  __shared__ __align__(16) unsigned short As[128][40];
  __shared__ __align__(16) unsigned short Bgs[128][40];
  __shared__ __align__(16) unsigned short Bus[128][40];
  int tid = threadIdx.x;
  int lane = tid & 63;
  int w = tid >> 6, wr = w >> 1, wc = w & 1;
  int fr = lane & 15, fq = lane >> 4;
  int fk = fq * 8;
  int arow = tid >> 1, ahalf = tid & 1;
  bool avalid = (m0 + arow) < cnt;
  int tok = ROUTED ? (avalid ? toklist[e * T_TOK + m0 + arow] : 0) : (m0 + arow);
  const unsigned short* aptr = X + (size_t)tok * K;
  int bn = tid & 127, bseg = tid >> 7;
  f32x4 zero = {0.f, 0.f, 0.f, 0.f};
  f32x4 accg[4][4], accu[4][4];
#pragma unroll
  for (int i = 0; i < 4; i++)
#pragma unroll
    for (int j = 0; j < 4; j++) { accg[i][j] = zero; accu[i][j] = zero; }
  for (int k0 = 0; k0 < K; k0 += 32) {
    uint4 v0 = make_uint4(0, 0, 0, 0), v1 = make_uint4(0, 0, 0, 0);
    if (avalid) {
      const uint4* p = (const uint4*)(aptr + k0 + ahalf * 16);
      v0 = p[0]; v1 = p[1];
    }
    *(uint4*)&As[arow][ahalf * 16] = v0;
    *(uint4*)&As[arow][ahalf * 16 + 8] = v1;
    {
      const float* wp = Bg + (size_t)(k0 + bseg * 16) * N + n0 + bn;
      unsigned int pk[8];
#pragma unroll
      for (int i = 0; i < 8; i++) {
        float f0 = wp[(size_t)(2 * i) * N];
        float f1 = wp[(size_t)(2 * i + 1) * N];
        pk[i] = (unsigned)f2bf(f0) | ((unsigned)f2bf(f1) << 16);
      }
      *(uint4*)&Bgs[bn][bseg * 16] = make_uint4(pk[0], pk[1], pk[2], pk[3]);
      *(uint4*)&Bgs[bn][bseg * 16 + 8] = make_uint4(pk[4], pk[5], pk[6], pk[7]);
    }
    {
      const float* wp = Bu + (size_t)(k0 + bseg * 16) * N + n0 + bn;
      unsigned int pk[8];
#pragma unroll
      for (int i = 0; i < 8; i++) {
        float f0 = wp[(size_t)(2 * i) * N];
        float f1 = wp[(size_t)(2 * i + 1) * N];
        pk[i] = (unsigned)f2bf(f0) | ((unsigned)f2bf(f1) << 16);
      }
      *(uint4*)&Bus[bn][bseg * 16] = make_uint4(pk[0], pk[1], pk[2], pk[3]);
      *(uint4*)&Bus[bn][bseg * 16 + 8] = make_uint4(pk[4], pk[5], pk[6], pk[7]);
    }
    __syncthreads();
    bf16x8 af[4], bgf[4], buf[4];
#pragma unroll
    for (int mi = 0; mi < 4; mi++)
      af[mi] = *(const bf16x8*)&As[wr * 64 + mi * 16 + fr][fk];
#pragma unroll
    for (int ni = 0; ni < 4; ni++) {
      bgf[ni] = *(const bf16x8*)&Bgs[wc * 64 + ni * 16 + fr][fk];
      buf[ni] = *(const bf16x8*)&Bus[wc * 64 + ni * 16 + fr][fk];
    }
#pragma unroll
    for (int mi = 0; mi < 4; mi++)
#pragma unroll
      for (int ni = 0; ni < 4; ni++) {
        accg[mi][ni] = __builtin_amdgcn_mfma_f32_16x16x32_bf16(af[mi], bgf[ni], accg[mi][ni], 0, 0, 0);
        accu[mi][ni] = __builtin_amdgcn_mfma_f32_16x16x32_bf16(af[mi], buf[ni], accu[mi][ni], 0, 0, 0);
      }
    __syncthreads();
  }
  int rbase = m0 + wr * 64;
  int cbase = n0 + wc * 64;
  size_t outbase = ROUTED ? (size_t)e * T_TOK : (size_t)0;
#pragma unroll
  for (int mi = 0; mi < 4; mi++)
#pragma unroll
    for (int ni = 0; ni < 4; ni++) {
      int col = cbase + ni * 16 + fr;
#pragma unroll
      for (int j = 0; j < 4; j++) {
        int row = rbase + mi * 16 + fq * 4 + j;
        if (row < cnt) {
          float g = accg[mi][ni][j];
          float u = accu[mi][ni][j];
          float h = g / (1.f + __expf(-g)) * u;
          Hout[(outbase + row) * (size_t)N + col] = f2bf(h);
        }
      }
    }
}

template <bool ROUTED>
__global__ __launch_bounds__(256) void gemm_down(
    const unsigned short* __restrict__ Hin, const float* __restrict__ WdAll,
    float* __restrict__ Out,
    const int* __restrict__ toklist, const float* __restrict__ wts,
    const int* __restrict__ counts, int K, int N) {
  int e = blockIdx.z;
  int m0 = blockIdx.y * 128;
  int n0 = blockIdx.x * 128;
  int cnt = ROUTED ? counts[e] : T_TOK;
  if (m0 >= cnt) return;
  const float* Bd = WdAll + (size_t)e * K * N;
  __shared__ __align__(16) unsigned short As[128][40];
  __shared__ __align__(16) unsigned short Bs[128][40];
  int tid = threadIdx.x;
  int lane = tid & 63;
  int w = tid >> 6, wr = w >> 1, wc = w & 1;
  int fr = lane & 15, fq = lane >> 4;
  int fk = fq * 8;
  int arow = tid >> 1, ahalf = tid & 1;
  bool avalid = (m0 + arow) < cnt;
  size_t abase = (ROUTED ? (size_t)e * T_TOK : (size_t)0) + m0 + arow;
  const unsigned short* aptr = Hin + abase * (size_t)K;
  int bn = tid & 127, bseg = tid >> 7;
  f32x4 zero = {0.f, 0.f, 0.f, 0.f};
  f32x4 acc[4][4];
#pragma unroll
  for (int i = 0; i < 4; i++)
#pragma unroll
    for (int j = 0; j < 4; j++) acc[i][j] = zero;
  for (int k0 = 0; k0 < K; k0 += 32) {
    uint4 v0 = make_uint4(0, 0, 0, 0), v1 = make_uint4(0, 0, 0, 0);
    if (avalid) {
      const uint4* p = (const uint4*)(aptr + k0 + ahalf * 16);
      v0 = p[0]; v1 = p[1];
    }
    *(uint4*)&As[arow][ahalf * 16] = v0;
    *(uint4*)&As[arow][ahalf * 16 + 8] = v1;
    {
      const float* wp = Bd + (size_t)(k0 + bseg * 16) * N + n0 + bn;
      unsigned int pk[8];
#pragma unroll
      for (int i = 0; i < 8; i++) {
        float f0 = wp[(size_t)(2 * i) * N];
        float f1 = wp[(size_t)(2 * i + 1) * N];
        pk[i] = (unsigned)f2bf(f0) | ((unsigned)f2bf(f1) << 16);
      }
      *(uint4*)&Bs[bn][bseg * 16] = make_uint4(pk[0], pk[1], pk[2], pk[3]);
      *(uint4*)&Bs[bn][bseg * 16 + 8] = make_uint4(pk[4], pk[5], pk[6], pk[7]);
    }
    __syncthreads();
    bf16x8 af[4], bf[4];
#pragma unroll
    for (int mi = 0; mi < 4; mi++)
      af[mi] = *(const bf16x8*)&As[wr * 64 + mi * 16 + fr][fk];
#pragma unroll
    for (int ni = 0; ni < 4; ni++)
      bf[ni] = *(const bf16x8*)&Bs[wc * 64 + ni * 16 + fr][fk];
#pragma unroll
    for (int mi = 0; mi < 4; mi++)
#pragma unroll
      for (int ni = 0; ni < 4; ni++)
        acc[mi][ni] = __builtin_amdgcn_mfma_f32_16x16x32_bf16(af[mi], bf[ni], acc[mi][ni], 0, 0, 0);
    __syncthreads();
  }
  int rbase = m0 + wr * 64;
  int cbase = n0 + wc * 64;
#pragma unroll
  for (int mi = 0; mi < 4; mi++)
#pragma unroll
    for (int ni = 0; ni < 4; ni++) {
      int col = cbase + ni * 16 + fr;
#pragma unroll
      for (int j = 0; j < 4; j++) {
        int row = rbase + mi * 16 + fq * 4 + j;
        if (row < cnt) {
          float v = acc[mi][ni][j];
          if (ROUTED) {
            int tk = toklist[e * T_TOK + row];
            float wgt = wts[e * T_TOK + row];
            atomicAdd(&Out[(size_t)tk * N + col], wgt * v);
          } else {
            Out[(size_t)row * N + col] = v;
          }
        }
      }
    }
}

extern "C" void kernel_launch(void* const* d_in, const int* in_sizes, int n_in,
                              void* d_out, int out_size, void* d_ws, size_t ws_size,
                              hipStream_t stream) {
  const float* x = (const float*)d_in[0];
  const int* labels = (const int*)d_in[1];
  const float* cc = (const float*)d_in[2];
  const float* Wg = (const float*)d_in[3];
  const float* Wu = (const float*)d_in[4];
  const float* Wd = (const float*)d_in[5];
  const float* Wgs = (const float*)d_in[6];
  const float* Wus = (const float*)d_in[7];
  const float* Wds = (const float*)d_in[8];
  float* out = (float*)d_out;

  // ---- fast-path workspace layout ----
  uint8_t* p = (uint8_t*)d_ws;
  int* counts = (int*)p;            p += 256;
  int* toklist = (int*)p;           p += (size_t)NE * T_TOK * 4;
  float* wts = (float*)p;           p += (size_t)NE * T_TOK * 4;
  unsigned short* xbf = (unsigned short*)p;  p += (size_t)T_TOK * H_DIM * 2;
  unsigned short* WgT = (unsigned short*)p;  p += (size_t)NE * H_DIM * IMOE * 2;
  unsigned short* WuT = (unsigned short*)p;  p += (size_t)NE * H_DIM * IMOE * 2;
  unsigned short* WdT = (unsigned short*)p;  p += (size_t)NE * IMOE * H_DIM * 2;
  unsigned short* WgsT = (unsigned short*)p; p += (size_t)H_DIM * ISHARED * 2;
  unsigned short* WusT = (unsigned short*)p; p += (size_t)H_DIM * ISHARED * 2;
  unsigned short* WdsT = (unsigned short*)p; p += (size_t)ISHARED * H_DIM * 2;
  unsigned short* HhT = (unsigned short*)p;  p += (size_t)NE * T_TOK * IMOE * 2;
  unsigned short* HsT = (unsigned short*)p;  p += (size_t)T_TOK * ISHARED * 2;
  size_t need = (size_t)(p - (uint8_t*)d_ws);

  hipMemsetAsync(d_ws, 0, 64, stream);
  cvt_bf16_kernel<<<(T_TOK * H_DIM / 4 + 255) / 256, 256, 0, stream>>>(x, xbf, T_TOK * H_DIM);
  router_kernel<<<T_TOK / 4, 256, 0, stream>>>(x, labels, cc, counts, toklist, wts);

  if (ws_size >= need) {
    // ---- fast path ----
    transpose_cvt<<<dim3(IMOE / 64, H_DIM / 32, NE), 256, 0, stream>>>(Wg, WgT, H_DIM, IMOE);
    transpose_cvt<<<dim3(IMOE / 64, H_DIM / 32, NE), 256, 0, stream>>>(Wu, WuT, H_DIM, IMOE);
    transpose_cvt<<<dim3(H_DIM / 64, IMOE / 32, NE), 256, 0, stream>>>(Wd, WdT, IMOE, H_DIM);
    transpose_cvt<<<dim3(ISHARED / 64, H_DIM / 32, 1), 256, 0, stream>>>(Wgs, WgsT, H_DIM, ISHARED);
    transpose_cvt<<<dim3(ISHARED / 64, H_DIM / 32, 1), 256, 0, stream>>>(Wus, WusT, H_DIM, ISHARED);
    transpose_cvt<<<dim3(H_DIM / 64, ISHARED / 32, 1), 256, 0, stream>>>(Wds, WdsT, ISHARED, H_DIM);

    gemm_up2<false><<<dim3(ISHARED / 128, T_TOK / 128, 1), 256, 0, stream>>>(
        xbf, WgsT, WusT, HsT, nullptr, nullptr, H_DIM, ISHARED);
    gemm_up2<true><<<dim3(IMOE / 128, T_TOK / 128, NE), 256, 0, stream>>>(
        xbf, WgT, WuT, HhT, toklist, counts, H_DIM, IMOE);

    gemm_down2<false><<<dim3(H_DIM / 128, T_TOK / 128, 1), 256, 0, stream>>>(
        HsT, WdsT, out, nullptr, nullptr, nullptr, ISHARED, H_DIM);
    gemm_down2<true><<<dim3(H_DIM / 128, T_TOK / 128, NE), 256, 0, stream>>>(
        HhT, WdT, out, toklist, wts, counts, IMOE, H_DIM);
  } else {
    // ---- fallback: round-1 layout reusing same ws head ----
    unsigned short* Hh = WgT;  // [NE][T][IMOE] bf16
    unsigned short* Hs = Hh + (size_t)NE * T_TOK * IMOE;  // [T][ISHARED] bf16

    gemm_up<false><<<dim3(ISHARED / 128, T_TOK / 128, 1), 256, 0, stream>>>(
        xbf, Wgs, Wus, Hs, nullptr, nullptr, H_DIM, ISHARED);
    gemm_up<true><<<dim3(IMOE / 128, T_TOK / 128, NE), 256, 0, stream>>>(
        xbf, Wg, Wu, Hh, toklist, counts, H_DIM, IMOE);

    gemm_down<false><<<dim3(H_DIM / 128, T_TOK / 128, 1), 256, 0, stream>>>(
        Hs, Wds, out, nullptr, nullptr, nullptr, ISHARED, H_DIM);
    gemm_down<true><<<dim3(H_DIM / 128, T_TOK / 128, NE), 256, 0, stream>>>(
        Hh, Wd, out, toklist, wts, counts, IMOE, H_DIM);
  }
}

// Round 4
// 578.993 us; speedup vs baseline: 1.2592x; 1.2592x over previous
//
#include <hip/hip_runtime.h>
#include <hip/hip_bf16.h>
#include <stdint.h>

#define T_TOK 2048
#define H_DIM 2048
#define S_SEQ 1024
#define NE_ROUTED 8
#define NE 9
#define IMOE 1408
#define ISHARED 5632
#define UNCOND_LBL 1000

typedef short bf16x8 __attribute__((ext_vector_type(8)));
typedef float f32x4 __attribute__((ext_vector_type(4)));

__device__ __forceinline__ unsigned short f2bf(float f) {
  union { float f; unsigned int u; } v; v.f = f;
  unsigned int u = v.u;
  return (unsigned short)((u + 0x7fffu + ((u >> 16) & 1u)) >> 16);
}

// async global->LDS, 16 B per lane; lds dest is wave-uniform base + lane*16
__device__ __forceinline__ void gl16(const void* g, void* l) {
  __builtin_amdgcn_global_load_lds(
      (const __attribute__((address_space(1))) unsigned int*)g,
      (__attribute__((address_space(3))) unsigned int*)l, 16, 0, 0);
}

// ---------------- convert x (f32) -> bf16 ----------------
__global__ __launch_bounds__(256) void cvt_bf16_kernel(const float* __restrict__ in,
                                                       unsigned short* __restrict__ out,
                                                       int n) {
  int i = (blockIdx.x * 256 + threadIdx.x) * 4;
  if (i >= n) return;
  float4 v = *(const float4*)(in + i);
  uint2 p;
  p.x = (unsigned)f2bf(v.x) | ((unsigned)f2bf(v.y) << 16);
  p.y = (unsigned)f2bf(v.z) | ((unsigned)f2bf(v.w) << 16);
  *(uint2*)(out + i) = p;
}

// ---------------- router: one wave per token ----------------
__global__ __launch_bounds__(256) void router_kernel(
    const float* __restrict__ x, const int* __restrict__ labels,
    const float* __restrict__ cc,
    int* __restrict__ counts, int* __restrict__ toklist, float* __restrict__ wts) {
  int t = (int)((blockIdx.x * 256 + threadIdx.x) >> 6);
  int lane = threadIdx.x & 63;
  if (t >= T_TOK) return;
  const float* xp = x + (size_t)t * H_DIM;
  float xx = 0.f;
  float d[NE_ROUTED], cn[NE_ROUTED];
#pragma unroll
  for (int e = 0; e < NE_ROUTED; e++) { d[e] = 0.f; cn[e] = 0.f; }
  for (int h = lane; h < H_DIM; h += 64) {
    float xv = xp[h];
    xx += xv * xv;
#pragma unroll
    for (int e = 0; e < NE_ROUTED; e++) {
      float cv = cc[e * H_DIM + h];
      d[e] += xv * cv;
      cn[e] += cv * cv;
    }
  }
#pragma unroll
  for (int off = 32; off > 0; off >>= 1) {
    xx += __shfl_xor(xx, off);
#pragma unroll
    for (int e = 0; e < NE_ROUTED; e++) {
      d[e] += __shfl_xor(d[e], off);
      cn[e] += __shfl_xor(cn[e], off);
    }
  }
  if (lane == 0) {
    int lab = labels[t / S_SEQ];
    if (lab == UNCOND_LBL) {
      int r = atomicAdd(&counts[NE - 1], 1);
      toklist[(NE - 1) * T_TOK + r] = t;
      wts[(NE - 1) * T_TOK + r] = 1.0f;
    } else {
      float xn = sqrtf(xx + 1e-12f);
      float cosv[NE_ROUTED];
      float mx = -1e30f;
#pragma unroll
      for (int e = 0; e < NE_ROUTED; e++) {
        cosv[e] = d[e] / (xn * sqrtf(cn[e] + 1e-12f));
        mx = fmaxf(mx, cosv[e]);
      }
      float p[NE_ROUTED];
      float s = 0.f;
#pragma unroll
      for (int e = 0; e < NE_ROUTED; e++) { p[e] = __expf(cosv[e] - mx); s += p[e]; }
      int i1 = 0;
#pragma unroll
      for (int e = 1; e < NE_ROUTED; e++) if (p[e] > p[i1]) i1 = e;
      int i2 = (i1 == 0) ? 1 : 0;
#pragma unroll
      for (int e = 0; e < NE_ROUTED; e++) if (e != i2 && e != i1 && p[e] > p[i2]) i2 = e;
      int r1 = atomicAdd(&counts[i1], 1);
      toklist[i1 * T_TOK + r1] = t;
      wts[i1 * T_TOK + r1] = p[i1] / s;
      int r2 = atomicAdd(&counts[i2], 1);
      toklist[i2 * T_TOK + r2] = t;
      wts[i2 * T_TOK + r2] = p[i2] / s;
    }
  }
}

// ============================================================================
// Striped-swizzled bf16 layout: tensor[e][ns][kt][u][8] where ns=n/16, kt=k/32,
// logical unit ul = (n&15)*4 + ((k>>3)&3), physical u = ul ^ ((ul>>3)&7)
// (involution: gl16 stages linearly, ds_read applies the same XOR -> 0 bank
// conflicts; verified rounds 2-3).
// ============================================================================

// Transpose+convert W[e][K][N] f32 -> striped W'[e][N/16][K/32][512] bf16.
__global__ __launch_bounds__(256) void transpose_cvt(
    const float* __restrict__ src, unsigned short* __restrict__ dst, int K, int N) {
  int e = blockIdx.z;
  int kt = blockIdx.y;          // 32 k rows
  int n0 = blockIdx.x << 6;     // 64 n cols = 4 stripes
  int NS = N >> 4, KT = K >> 5;
  const float* sp0 = src + (size_t)e * K * N + (size_t)kt * 32 * N + n0;
  __shared__ float tile[32][72];
  int t = threadIdx.x;
  int kr = t >> 3, nc = (t & 7) << 3;
  const float* sp = sp0 + (size_t)kr * N + nc;
  float4 a = *(const float4*)sp;
  float4 b = *(const float4*)(sp + 4);
  *(float4*)&tile[kr][nc] = a;
  *(float4*)&tile[kr][nc + 4] = b;
  __syncthreads();
  int nsl = t >> 6, up = t & 63;
  int ul = up ^ ((up >> 3) & 7);
  int rn = ul >> 2, fq = ul & 3;
  int nl = (nsl << 4) + rn;
  unsigned int pk[4];
#pragma unroll
  for (int j = 0; j < 4; j++) {
    float f0 = tile[fq * 8 + 2 * j][nl];
    float f1 = tile[fq * 8 + 2 * j + 1][nl];
    pk[j] = (unsigned)f2bf(f0) | ((unsigned)f2bf(f1) << 16);
  }
  size_t ns = (size_t)e * NS + (n0 >> 4) + nsl;
  unsigned short* dp = dst + (ns * KT + kt) * 512 + up * 8;
  *(uint4*)dp = make_uint4(pk[0], pk[1], pk[2], pk[3]);
}

// ============================================================================
// Fused gate+up GEMM: BM=256 BN=128 BK=32, 8 waves (4m x 2n, wave-tile 64x64),
// 4-buffer LDS ring, depth-3 prefetch, counted vmcnt, 1 barrier per K-step.
// ============================================================================
template <bool ROUTED>
__global__ __launch_bounds__(512) void gemm_up8(
    const unsigned short* __restrict__ X,     // [T][K] bf16 row-major
    const unsigned short* __restrict__ WgT,   // striped
    const unsigned short* __restrict__ WuT,   // striped
    unsigned short* __restrict__ Hout,        // striped [e][T/16][N/32][512]
    const int* __restrict__ toklist, const int* __restrict__ counts,
    int K, int N) {
  int e = ROUTED ? blockIdx.z : 0;
  int m0 = blockIdx.y * 256;
  int n0 = blockIdx.x * 128;
  int cnt = ROUTED ? counts[e] : T_TOK;
  if (m0 >= cnt) return;
  int KT = K >> 5;
  int NS = N >> 4;
  int MS = T_TOK >> 4;
  int KTO = N >> 5;

  __shared__ unsigned short As[4][8192];   // 16 subtiles x 512
  __shared__ unsigned short Bgs[4][4096];  // 8 subtiles x 512
  __shared__ unsigned short Bus[4][4096];

  int tid = threadIdx.x, lane = tid & 63, wid = tid >> 6;
  int wm = wid >> 1, wn = wid & 1;
  int fr = lane & 15, fq = lane >> 4;

  // per-lane pre-swizzled A gather sources (2 subtiles per wave)
  int v = lane ^ ((lane >> 3) & 7);
  const unsigned short* aptr[2];
#pragma unroll
  for (int i = 0; i < 2; i++) {
    int r = m0 + (wid * 2 + i) * 16 + (v >> 2);
    if (r >= cnt) r = cnt - 1;
    int tok = ROUTED ? toklist[e * T_TOK + r] : r;
    aptr[i] = X + (size_t)tok * K + ((v & 3) << 3);
  }
  // B sources: 1 subtile per wave
  size_t nsg = (size_t)e * NS + (n0 >> 4) + wid;
  const unsigned short* bgp = WgT + nsg * KT * 512 + lane * 8;
  const unsigned short* bup = WuT + nsg * KT * 512 + lane * 8;

  int fo = fr * 4 + fq;
  fo = (fo ^ ((fo >> 3) & 7)) * 8;

  f32x4 zero = {0.f, 0.f, 0.f, 0.f};
  f32x4 accg[4][4], accu[4][4];
#pragma unroll
  for (int i = 0; i < 4; i++)
#pragma unroll
    for (int j = 0; j < 4; j++) { accg[i][j] = zero; accu[i][j] = zero; }

  auto stageA = [&](int b, int t) {
#pragma unroll
    for (int i = 0; i < 2; i++)
      gl16(aptr[i] + (size_t)t * 32, &As[b][(wid * 2 + i) * 512]);
  };
  auto stageB = [&](int b, int t) {
    gl16(bgp + (size_t)t * 512, &Bgs[b][wid * 512]);
    gl16(bup + (size_t)t * 512, &Bus[b][wid * 512]);
  };

  // prologue: 3 tiles in flight (4 loads/thread each, order A,A,Bg,Bu)
  stageA(0, 0); stageB(0, 0);
  stageA(1, 1); stageB(1, 1);
  stageA(2, 2); stageB(2, 2);
  asm volatile("s_waitcnt vmcnt(8)" ::: "memory");   // tile 0 landed
  __builtin_amdgcn_s_barrier();

  for (int t = 0; t < KT; ++t) {
    int b = t & 3;
    // ---- phase 1: A + Bg reads, A prefetch, gate MFMAs ----
    bf16x8 af[4], bgf[4];
#pragma unroll
    for (int mi = 0; mi < 4; mi++)
      af[mi] = *(const bf16x8*)&As[b][(wm * 4 + mi) * 512 + fo];
#pragma unroll
    for (int ni = 0; ni < 4; ni++)
      bgf[ni] = *(const bf16x8*)&Bgs[b][(wn * 4 + ni) * 512 + fo];
    if (t + 3 < KT) stageA((t + 3) & 3, t + 3);
    __builtin_amdgcn_s_setprio(1);
#pragma unroll
    for (int mi = 0; mi < 4; mi++)
#pragma unroll
      for (int ni = 0; ni < 4; ni++)
        accg[mi][ni] = __builtin_amdgcn_mfma_f32_16x16x32_bf16(af[mi], bgf[ni], accg[mi][ni], 0, 0, 0);
    __builtin_amdgcn_s_setprio(0);
    // ---- phase 2: Bu reads, B prefetch, up MFMAs ----
    bf16x8 buf2[4];
#pragma unroll
    for (int ni = 0; ni < 4; ni++)
      buf2[ni] = *(const bf16x8*)&Bus[b][(wn * 4 + ni) * 512 + fo];
    if (t + 3 < KT) stageB((t + 3) & 3, t + 3);
    __builtin_amdgcn_s_setprio(1);
#pragma unroll
    for (int mi = 0; mi < 4; mi++)
#pragma unroll
      for (int ni = 0; ni < 4; ni++)
        accu[mi][ni] = __builtin_amdgcn_mfma_f32_16x16x32_bf16(af[mi], buf2[ni], accu[mi][ni], 0, 0, 0);
    __builtin_amdgcn_s_setprio(0);
    // ---- publish next tile ----
    if (t + 3 < KT) {
      asm volatile("s_waitcnt vmcnt(8)" ::: "memory");
      __builtin_amdgcn_s_barrier();
    } else if (t + 2 < KT) {
      asm volatile("s_waitcnt vmcnt(4)" ::: "memory");
      __builtin_amdgcn_s_barrier();
    } else if (t + 1 < KT) {
      asm volatile("s_waitcnt vmcnt(0)" ::: "memory");
      __builtin_amdgcn_s_barrier();
    }
  }

  // epilogue: silu(g)*u -> bf16, write striped Hout
  size_t hb = (size_t)e * MS;
#pragma unroll
  for (int mi = 0; mi < 4; mi++) {
    int rb = m0 + wm * 64 + mi * 16;
    if (rb >= cnt) continue;
    int ms = rb >> 4;
#pragma unroll
    for (int ni = 0; ni < 4; ni++) {
      int col = n0 + wn * 64 + ni * 16 + fr;
      int kto = col >> 5;
      int c3 = (col >> 3) & 3;
      int j = col & 7;
      size_t base = ((hb + ms) * (size_t)KTO + kto) * 512 + j;
#pragma unroll
      for (int jj = 0; jj < 4; jj++) {
        int row = rb + fq * 4 + jj;
        if (row < cnt) {
          float g = accg[mi][ni][jj];
          float u = accu[mi][ni][jj];
          float h = g / (1.f + __expf(-g)) * u;
          int ul = (fq * 4 + jj) * 4 + c3;
          int ph = ul ^ ((ul >> 3) & 7);
          Hout[base + ph * 8] = f2bf(h);
        }
      }
    }
  }
}

// ============================================================================
// Down GEMM: same skeleton, single B; routed -> weighted atomicAdd scatter.
// ============================================================================
template <bool ROUTED>
__global__ __launch_bounds__(512) void gemm_down8(
    const unsigned short* __restrict__ HinT,  // striped [e][T/16][K/32][512]
    const unsigned short* __restrict__ WdT,   // striped
    float* __restrict__ Out,
    const int* __restrict__ toklist, const float* __restrict__ wts,
    const int* __restrict__ counts, int K, int N) {
  int e = ROUTED ? blockIdx.z : 0;
  int m0 = blockIdx.y * 256;
  int n0 = blockIdx.x * 128;
  int cnt = ROUTED ? counts[e] : T_TOK;
  if (m0 >= cnt) return;
  int KT = K >> 5;
  int NS = N >> 4;
  int MS = T_TOK >> 4;

  __shared__ unsigned short As[4][8192];
  __shared__ unsigned short Bs[4][4096];

  int tid = threadIdx.x, lane = tid & 63, wid = tid >> 6;
  int wm = wid >> 1, wn = wid & 1;
  int fr = lane & 15, fq = lane >> 4;

  const unsigned short* ap[2];
#pragma unroll
  for (int i = 0; i < 2; i++) {
    size_t ms = (size_t)e * MS + (m0 >> 4) + wid * 2 + i;
    ap[i] = HinT + ms * KT * 512 + lane * 8;
  }
  size_t nsg = (size_t)e * NS + (n0 >> 4) + wid;
  const unsigned short* bp = WdT + nsg * KT * 512 + lane * 8;

  int fo = fr * 4 + fq;
  fo = (fo ^ ((fo >> 3) & 7)) * 8;

  f32x4 zero = {0.f, 0.f, 0.f, 0.f};
  f32x4 acc[4][4];
#pragma unroll
  for (int i = 0; i < 4; i++)
#pragma unroll
    for (int j = 0; j < 4; j++) acc[i][j] = zero;

  auto stageA = [&](int b, int t) {
#pragma unroll
    for (int i = 0; i < 2; i++)
      gl16(ap[i] + (size_t)t * 512, &As[b][(wid * 2 + i) * 512]);
  };
  auto stageB = [&](int b, int t) {
    gl16(bp + (size_t)t * 512, &Bs[b][wid * 512]);
  };

  stageA(0, 0); stageB(0, 0);
  stageA(1, 1); stageB(1, 1);
  stageA(2, 2); stageB(2, 2);
  asm volatile("s_waitcnt vmcnt(6)" ::: "memory");
  __builtin_amdgcn_s_barrier();

  for (int t = 0; t < KT; ++t) {
    int b = t & 3;
    bf16x8 af[4], bf[4];
#pragma unroll
    for (int mi = 0; mi < 4; mi++)
      af[mi] = *(const bf16x8*)&As[b][(wm * 4 + mi) * 512 + fo];
#pragma unroll
    for (int ni = 0; ni < 2; ni++)
      bf[ni] = *(const bf16x8*)&Bs[b][(wn * 4 + ni) * 512 + fo];
    if (t + 3 < KT) stageA((t + 3) & 3, t + 3);
    __builtin_amdgcn_s_setprio(1);
#pragma unroll
    for (int mi = 0; mi < 4; mi++)
#pragma unroll
      for (int ni = 0; ni < 2; ni++)
        acc[mi][ni] = __builtin_amdgcn_mfma_f32_16x16x32_bf16(af[mi], bf[ni], acc[mi][ni], 0, 0, 0);
    __builtin_amdgcn_s_setprio(0);
#pragma unroll
    for (int ni = 2; ni < 4; ni++)
      bf[ni] = *(const bf16x8*)&Bs[b][(wn * 4 + ni) * 512 + fo];
    if (t + 3 < KT) stageB((t + 3) & 3, t + 3);
    __builtin_amdgcn_s_setprio(1);
#pragma unroll
    for (int mi = 0; mi < 4; mi++)
#pragma unroll
      for (int ni = 2; ni < 4; ni++)
        acc[mi][ni] = __builtin_amdgcn_mfma_f32_16x16x32_bf16(af[mi], bf[ni], acc[mi][ni], 0, 0, 0);
    __builtin_amdgcn_s_setprio(0);
    if (t + 3 < KT) {
      asm volatile("s_waitcnt vmcnt(6)" ::: "memory");
      __builtin_amdgcn_s_barrier();
    } else if (t + 2 < KT) {
      asm volatile("s_waitcnt vmcnt(3)" ::: "memory");
      __builtin_amdgcn_s_barrier();
    } else if (t + 1 < KT) {
      asm volatile("s_waitcnt vmcnt(0)" ::: "memory");
      __builtin_amdgcn_s_barrier();
    }
  }

  int rbase = m0 + wm * 64;
  int cbase = n0 + wn * 64;
#pragma unroll
  for (int mi = 0; mi < 4; mi++)
#pragma unroll
    for (int ni = 0; ni < 4; ni++) {
      int col = cbase + ni * 16 + fr;
#pragma unroll
      for (int jj = 0; jj < 4; jj++) {
        int row = rbase + mi * 16 + fq * 4 + jj;
        if (row < cnt) {
          float vv = acc[mi][ni][jj];
          if (ROUTED) {
            int tk = toklist[e * T_TOK + row];
            float wgt = wts[e * T_TOK + row];
            atomicAdd(&Out[(size_t)tk * N + col], wgt * vv);
          } else {
            Out[(size_t)row * N + col] = vv;
          }
        }
      }
    }
}

extern "C" void kernel_launch(void* const* d_in, const int* in_sizes, int n_in,
                              void* d_out, int out_size, void* d_ws, size_t ws_size,
                              hipStream_t stream) {
  const float* x = (const float*)d_in[0];
  const int* labels = (const int*)d_in[1];
  const float* cc = (const float*)d_in[2];
  const float* Wg = (const float*)d_in[3];
  const float* Wu = (const float*)d_in[4];
  const float* Wd = (const float*)d_in[5];
  const float* Wgs = (const float*)d_in[6];
  const float* Wus = (const float*)d_in[7];
  const float* Wds = (const float*)d_in[8];
  float* out = (float*)d_out;

  // ---- workspace layout ----
  uint8_t* p = (uint8_t*)d_ws;
  int* counts = (int*)p;            p += 256;
  int* toklist = (int*)p;           p += (size_t)NE * T_TOK * 4;
  float* wts = (float*)p;           p += (size_t)NE * T_TOK * 4;
  unsigned short* xbf = (unsigned short*)p;  p += (size_t)T_TOK * H_DIM * 2;
  unsigned short* WgT = (unsigned short*)p;  p += (size_t)NE * H_DIM * IMOE * 2;
  unsigned short* WuT = (unsigned short*)p;  p += (size_t)NE * H_DIM * IMOE * 2;
  unsigned short* WdT = (unsigned short*)p;  p += (size_t)NE * IMOE * H_DIM * 2;
  unsigned short* WgsT = (unsigned short*)p; p += (size_t)H_DIM * ISHARED * 2;
  unsigned short* WusT = (unsigned short*)p; p += (size_t)H_DIM * ISHARED * 2;
  unsigned short* WdsT = (unsigned short*)p; p += (size_t)ISHARED * H_DIM * 2;
  unsigned short* HhT = (unsigned short*)p;  p += (size_t)NE * T_TOK * IMOE * 2;
  unsigned short* HsT = (unsigned short*)p;  p += (size_t)T_TOK * ISHARED * 2;
  size_t need = (size_t)(p - (uint8_t*)d_ws);
  if (ws_size < need) return;  // fail visibly (harness validates output)

  hipMemsetAsync(d_ws, 0, 64, stream);
  cvt_bf16_kernel<<<(T_TOK * H_DIM / 4 + 255) / 256, 256, 0, stream>>>(x, xbf, T_TOK * H_DIM);
  router_kernel<<<T_TOK / 4, 256, 0, stream>>>(x, labels, cc, counts, toklist, wts);

  transpose_cvt<<<dim3(IMOE / 64, H_DIM / 32, NE), 256, 0, stream>>>(Wg, WgT, H_DIM, IMOE);
  transpose_cvt<<<dim3(IMOE / 64, H_DIM / 32, NE), 256, 0, stream>>>(Wu, WuT, H_DIM, IMOE);
  transpose_cvt<<<dim3(H_DIM / 64, IMOE / 32, NE), 256, 0, stream>>>(Wd, WdT, IMOE, H_DIM);
  transpose_cvt<<<dim3(ISHARED / 64, H_DIM / 32, 1), 256, 0, stream>>>(Wgs, WgsT, H_DIM, ISHARED);
  transpose_cvt<<<dim3(ISHARED / 64, H_DIM / 32, 1), 256, 0, stream>>>(Wus, WusT, H_DIM, ISHARED);
  transpose_cvt<<<dim3(H_DIM / 64, ISHARED / 32, 1), 256, 0, stream>>>(Wds, WdsT, ISHARED, H_DIM);

  gemm_up8<false><<<dim3(ISHARED / 128, T_TOK / 256, 1), 512, 0, stream>>>(
      xbf, WgsT, WusT, HsT, nullptr, nullptr, H_DIM, ISHARED);
  gemm_up8<true><<<dim3(IMOE / 128, T_TOK / 256, NE), 512, 0, stream>>>(
      xbf, WgT, WuT, HhT, toklist, counts, H_DIM, IMOE);

  gemm_down8<false><<<dim3(H_DIM / 128, T_TOK / 256, 1), 512, 0, stream>>>(
      HsT, WdsT, out, nullptr, nullptr, nullptr, ISHARED, H_DIM);
  gemm_down8<true><<<dim3(H_DIM / 128, T_TOK / 256, NE), 512, 0, stream>>>(
      HhT, WdT, out, toklist, wts, counts, IMOE, H_DIM);
}

// Round 5
// 572.479 us; speedup vs baseline: 1.2736x; 1.0114x over previous
//
#include <hip/hip_runtime.h>
#include <hip/hip_bf16.h>
#include <stdint.h>

#define T_TOK 2048
#define H_DIM 2048
#define S_SEQ 1024
#define NE_ROUTED 8
#define NE 9
#define IMOE 1408
#define ISHARED 5632
#define UNCOND_LBL 1000

typedef short bf16x8 __attribute__((ext_vector_type(8)));
typedef float f32x4 __attribute__((ext_vector_type(4)));

__device__ __forceinline__ unsigned short f2bf(float f) {
  union { float f; unsigned int u; } v; v.f = f;
  unsigned int u = v.u;
  return (unsigned short)((u + 0x7fffu + ((u >> 16) & 1u)) >> 16);
}

// async global->LDS, 16 B per lane; lds dest is wave-uniform base + lane*16
__device__ __forceinline__ void gl16(const void* g, void* l) {
  __builtin_amdgcn_global_load_lds(
      (const __attribute__((address_space(1))) unsigned int*)g,
      (__attribute__((address_space(3))) unsigned int*)l, 16, 0, 0);
}

// bijective XCD chunk swizzle (m204): hardware dispatch id d (x-fastest,
// XCD ~ d%8) -> logical id so each XCD gets a contiguous logical chunk.
// Decompose logical id m-fastest so all m-blocks of one B-panel share an XCD L2.
__device__ __forceinline__ void xcd_remap(int gx, int gy, int* mt, int* nt) {
  int d = blockIdx.y * gx + blockIdx.x;
  int nwg = gx * gy;
  int q = nwg >> 3, r = nwg & 7;
  int xcd = d & 7, off = d >> 3;
  int wgid = (xcd < r ? xcd * (q + 1) : r * (q + 1) + (xcd - r) * q) + off;
  *mt = wgid % gy;
  *nt = wgid / gy;
}

// ---------------- convert x (f32) -> bf16 ----------------
__global__ __launch_bounds__(256) void cvt_bf16_kernel(const float* __restrict__ in,
                                                       unsigned short* __restrict__ out,
                                                       int n) {
  int i = (blockIdx.x * 256 + threadIdx.x) * 4;
  if (i >= n) return;
  float4 v = *(const float4*)(in + i);
  uint2 p;
  p.x = (unsigned)f2bf(v.x) | ((unsigned)f2bf(v.y) << 16);
  p.y = (unsigned)f2bf(v.z) | ((unsigned)f2bf(v.w) << 16);
  *(uint2*)(out + i) = p;
}

// ---------------- router: one wave per token ----------------
__global__ __launch_bounds__(256) void router_kernel(
    const float* __restrict__ x, const int* __restrict__ labels,
    const float* __restrict__ cc,
    int* __restrict__ counts, int* __restrict__ toklist, float* __restrict__ wts) {
  int t = (int)((blockIdx.x * 256 + threadIdx.x) >> 6);
  int lane = threadIdx.x & 63;
  if (t >= T_TOK) return;
  const float* xp = x + (size_t)t * H_DIM;
  float xx = 0.f;
  float d[NE_ROUTED], cn[NE_ROUTED];
#pragma unroll
  for (int e = 0; e < NE_ROUTED; e++) { d[e] = 0.f; cn[e] = 0.f; }
  for (int h = lane; h < H_DIM; h += 64) {
    float xv = xp[h];
    xx += xv * xv;
#pragma unroll
    for (int e = 0; e < NE_ROUTED; e++) {
      float cv = cc[e * H_DIM + h];
      d[e] += xv * cv;
      cn[e] += cv * cv;
    }
  }
#pragma unroll
  for (int off = 32; off > 0; off >>= 1) {
    xx += __shfl_xor(xx, off);
#pragma unroll
    for (int e = 0; e < NE_ROUTED; e++) {
      d[e] += __shfl_xor(d[e], off);
      cn[e] += __shfl_xor(cn[e], off);
    }
  }
  if (lane == 0) {
    int lab = labels[t / S_SEQ];
    if (lab == UNCOND_LBL) {
      int r = atomicAdd(&counts[NE - 1], 1);
      toklist[(NE - 1) * T_TOK + r] = t;
      wts[(NE - 1) * T_TOK + r] = 1.0f;
    } else {
      float xn = sqrtf(xx + 1e-12f);
      float cosv[NE_ROUTED];
      float mx = -1e30f;
#pragma unroll
      for (int e = 0; e < NE_ROUTED; e++) {
        cosv[e] = d[e] / (xn * sqrtf(cn[e] + 1e-12f));
        mx = fmaxf(mx, cosv[e]);
      }
      float p[NE_ROUTED];
      float s = 0.f;
#pragma unroll
      for (int e = 0; e < NE_ROUTED; e++) { p[e] = __expf(cosv[e] - mx); s += p[e]; }
      int i1 = 0;
#pragma unroll
      for (int e = 1; e < NE_ROUTED; e++) if (p[e] > p[i1]) i1 = e;
      int i2 = (i1 == 0) ? 1 : 0;
#pragma unroll
      for (int e = 0; e < NE_ROUTED; e++) if (e != i2 && e != i1 && p[e] > p[i2]) i2 = e;
      int r1 = atomicAdd(&counts[i1], 1);
      toklist[i1 * T_TOK + r1] = t;
      wts[i1 * T_TOK + r1] = p[i1] / s;
      int r2 = atomicAdd(&counts[i2], 1);
      toklist[i2 * T_TOK + r2] = t;
      wts[i2 * T_TOK + r2] = p[i2] / s;
    }
  }
}

// ============================================================================
// Striped-swizzled bf16 layout: tensor[e][ns][kt][u][8] where ns=n/16, kt=k/32,
// logical unit ul = (n&15)*4 + ((k>>3)&3), physical u = ul ^ ((ul>>3)&7)
// (involution: gl16 stages linearly, ds_read applies the same XOR -> 0 bank
// conflicts; verified rounds 2-4).
// ============================================================================

// Transpose+convert W[e][K][N] f32 -> striped W'[e][N/16][K/32][512] bf16.
__global__ __launch_bounds__(256) void transpose_cvt(
    const float* __restrict__ src, unsigned short* __restrict__ dst, int K, int N) {
  int e = blockIdx.z;
  int kt = blockIdx.y;          // 32 k rows
  int n0 = blockIdx.x << 6;     // 64 n cols = 4 stripes
  int NS = N >> 4, KT = K >> 5;
  const float* sp0 = src + (size_t)e * K * N + (size_t)kt * 32 * N + n0;
  __shared__ float tile[32][72];
  int t = threadIdx.x;
  int kr = t >> 3, nc = (t & 7) << 3;
  const float* sp = sp0 + (size_t)kr * N + nc;
  float4 a = *(const float4*)sp;
  float4 b = *(const float4*)(sp + 4);
  *(float4*)&tile[kr][nc] = a;
  *(float4*)&tile[kr][nc + 4] = b;
  __syncthreads();
  int nsl = t >> 6, up = t & 63;
  int ul = up ^ ((up >> 3) & 7);
  int rn = ul >> 2, fq = ul & 3;
  int nl = (nsl << 4) + rn;
  unsigned int pk[4];
#pragma unroll
  for (int j = 0; j < 4; j++) {
    float f0 = tile[fq * 8 + 2 * j][nl];
    float f1 = tile[fq * 8 + 2 * j + 1][nl];
    pk[j] = (unsigned)f2bf(f0) | ((unsigned)f2bf(f1) << 16);
  }
  size_t ns = (size_t)e * NS + (n0 >> 4) + nsl;
  unsigned short* dp = dst + (ns * KT + kt) * 512 + up * 8;
  *(uint4*)dp = make_uint4(pk[0], pk[1], pk[2], pk[3]);
}

// ============================================================================
// Fused gate+up GEMM: BM=256 BN=128 BK=32, 8 waves (4m x 2n, wave-tile 64x64),
// 4-buffer LDS ring, depth-3 prefetch, counted vmcnt, XCD chunk swizzle.
// ============================================================================
template <bool ROUTED>
__global__ __launch_bounds__(512) void gemm_up8(
    const unsigned short* __restrict__ X,     // [T][K] bf16 row-major
    const unsigned short* __restrict__ WgT,   // striped
    const unsigned short* __restrict__ WuT,   // striped
    unsigned short* __restrict__ Hout,        // striped [e][T/16][N/32][512]
    const int* __restrict__ toklist, const int* __restrict__ counts,
    int K, int N) {
  int e = ROUTED ? blockIdx.z : 0;
  int mt, nt;
  xcd_remap(gridDim.x, gridDim.y, &mt, &nt);
  int m0 = mt * 256;
  int n0 = nt * 128;
  int cnt = ROUTED ? counts[e] : T_TOK;
  if (m0 >= cnt) return;
  int KT = K >> 5;
  int NS = N >> 4;
  int MS = T_TOK >> 4;
  int KTO = N >> 5;

  __shared__ unsigned short As[4][8192];   // 16 subtiles x 512
  __shared__ unsigned short Bgs[4][4096];  // 8 subtiles x 512
  __shared__ unsigned short Bus[4][4096];

  int tid = threadIdx.x, lane = tid & 63, wid = tid >> 6;
  int wm = wid >> 1, wn = wid & 1;
  int fr = lane & 15, fq = lane >> 4;

  // per-lane pre-swizzled A gather sources (2 subtiles per wave)
  int v = lane ^ ((lane >> 3) & 7);
  const unsigned short* aptr[2];
#pragma unroll
  for (int i = 0; i < 2; i++) {
    int r = m0 + (wid * 2 + i) * 16 + (v >> 2);
    if (r >= cnt) r = cnt - 1;
    int tok = ROUTED ? toklist[e * T_TOK + r] : r;
    aptr[i] = X + (size_t)tok * K + ((v & 3) << 3);
  }
  // B sources: 1 subtile per wave
  size_t nsg = (size_t)e * NS + (n0 >> 4) + wid;
  const unsigned short* bgp = WgT + nsg * KT * 512 + lane * 8;
  const unsigned short* bup = WuT + nsg * KT * 512 + lane * 8;

  int fo = fr * 4 + fq;
  fo = (fo ^ ((fo >> 3) & 7)) * 8;

  f32x4 zero = {0.f, 0.f, 0.f, 0.f};
  f32x4 accg[4][4], accu[4][4];
#pragma unroll
  for (int i = 0; i < 4; i++)
#pragma unroll
    for (int j = 0; j < 4; j++) { accg[i][j] = zero; accu[i][j] = zero; }

  auto stageA = [&](int b, int t) {
#pragma unroll
    for (int i = 0; i < 2; i++)
      gl16(aptr[i] + (size_t)t * 32, &As[b][(wid * 2 + i) * 512]);
  };
  auto stageB = [&](int b, int t) {
    gl16(bgp + (size_t)t * 512, &Bgs[b][wid * 512]);
    gl16(bup + (size_t)t * 512, &Bus[b][wid * 512]);
  };

  // prologue: 3 tiles in flight (4 loads/thread each)
  stageA(0, 0); stageB(0, 0);
  stageA(1, 1); stageB(1, 1);
  stageA(2, 2); stageB(2, 2);
  asm volatile("s_waitcnt vmcnt(8)" ::: "memory");   // tile 0 landed
  __builtin_amdgcn_s_barrier();

  for (int t = 0; t < KT; ++t) {
    int b = t & 3;
    // ---- phase 1: A + Bg reads, A prefetch, gate MFMAs ----
    bf16x8 af[4], bgf[4];
#pragma unroll
    for (int mi = 0; mi < 4; mi++)
      af[mi] = *(const bf16x8*)&As[b][(wm * 4 + mi) * 512 + fo];
#pragma unroll
    for (int ni = 0; ni < 4; ni++)
      bgf[ni] = *(const bf16x8*)&Bgs[b][(wn * 4 + ni) * 512 + fo];
    if (t + 3 < KT) stageA((t + 3) & 3, t + 3);
    __builtin_amdgcn_s_setprio(1);
#pragma unroll
    for (int mi = 0; mi < 4; mi++)
#pragma unroll
      for (int ni = 0; ni < 4; ni++)
        accg[mi][ni] = __builtin_amdgcn_mfma_f32_16x16x32_bf16(af[mi], bgf[ni], accg[mi][ni], 0, 0, 0);
    __builtin_amdgcn_s_setprio(0);
    // ---- phase 2: Bu reads, B prefetch, up MFMAs ----
    bf16x8 buf2[4];
#pragma unroll
    for (int ni = 0; ni < 4; ni++)
      buf2[ni] = *(const bf16x8*)&Bus[b][(wn * 4 + ni) * 512 + fo];
    if (t + 3 < KT) stageB((t + 3) & 3, t + 3);
    __builtin_amdgcn_s_setprio(1);
#pragma unroll
    for (int mi = 0; mi < 4; mi++)
#pragma unroll
      for (int ni = 0; ni < 4; ni++)
        accu[mi][ni] = __builtin_amdgcn_mfma_f32_16x16x32_bf16(af[mi], buf2[ni], accu[mi][ni], 0, 0, 0);
    __builtin_amdgcn_s_setprio(0);
    // ---- publish next tile ----
    if (t + 3 < KT) {
      asm volatile("s_waitcnt vmcnt(8)" ::: "memory");
      __builtin_amdgcn_s_barrier();
    } else if (t + 2 < KT) {
      asm volatile("s_waitcnt vmcnt(4)" ::: "memory");
      __builtin_amdgcn_s_barrier();
    } else if (t + 1 < KT) {
      asm volatile("s_waitcnt vmcnt(0)" ::: "memory");
      __builtin_amdgcn_s_barrier();
    }
  }

  // epilogue: silu(g)*u -> bf16, write striped Hout
  size_t hb = (size_t)e * MS;
#pragma unroll
  for (int mi = 0; mi < 4; mi++) {
    int rb = m0 + wm * 64 + mi * 16;
    if (rb >= cnt) continue;
    int ms = rb >> 4;
#pragma unroll
    for (int ni = 0; ni < 4; ni++) {
      int col = n0 + wn * 64 + ni * 16 + fr;
      int kto = col >> 5;
      int c3 = (col >> 3) & 3;
      int j = col & 7;
      size_t base = ((hb + ms) * (size_t)KTO + kto) * 512 + j;
#pragma unroll
      for (int jj = 0; jj < 4; jj++) {
        int row = rb + fq * 4 + jj;
        if (row < cnt) {
          float g = accg[mi][ni][jj];
          float u = accu[mi][ni][jj];
          float h = g / (1.f + __expf(-g)) * u;
          int ul = (fq * 4 + jj) * 4 + c3;
          int ph = ul ^ ((ul >> 3) & 7);
          Hout[base + ph * 8] = f2bf(h);
        }
      }
    }
  }
}

// ============================================================================
// Down GEMM: BM=128 BN=128 BK=32, 8 waves (2m x 4n, wave-tile 64x32),
// 4-ring (64 KB LDS -> 2 blocks/CU), uniform 2 loads/wave/tile, XCD swizzle.
// ============================================================================
template <bool ROUTED>
__global__ __launch_bounds__(512, 4) void gemm_down8(
    const unsigned short* __restrict__ HinT,  // striped [e][T/16][K/32][512]
    const unsigned short* __restrict__ WdT,   // striped
    float* __restrict__ Out,
    const int* __restrict__ toklist, const float* __restrict__ wts,
    const int* __restrict__ counts, int K, int N) {
  int e = ROUTED ? blockIdx.z : 0;
  int mt, nt;
  xcd_remap(gridDim.x, gridDim.y, &mt, &nt);
  int m0 = mt * 128;
  int n0 = nt * 128;
  int cnt = ROUTED ? counts[e] : T_TOK;
  if (m0 >= cnt) return;
  int KT = K >> 5;
  int NS = N >> 4;
  int MS = T_TOK >> 4;

  __shared__ unsigned short As[4][4096];  // 8 subtiles x 512
  __shared__ unsigned short Bs[4][4096];

  int tid = threadIdx.x, lane = tid & 63, wid = tid >> 6;
  int wm = wid >> 2, wn = wid & 3;   // 2m x 4n
  int fr = lane & 15, fq = lane >> 4;

  size_t ms = (size_t)e * MS + (m0 >> 4) + wid;
  const unsigned short* ap = HinT + ms * KT * 512 + lane * 8;
  size_t nsg = (size_t)e * NS + (n0 >> 4) + wid;
  const unsigned short* bp = WdT + nsg * KT * 512 + lane * 8;

  int fo = fr * 4 + fq;
  fo = (fo ^ ((fo >> 3) & 7)) * 8;

  f32x4 zero = {0.f, 0.f, 0.f, 0.f};
  f32x4 acc[4][2];
#pragma unroll
  for (int i = 0; i < 4; i++)
#pragma unroll
    for (int j = 0; j < 2; j++) acc[i][j] = zero;

  auto stage = [&](int b, int t) {
    gl16(ap + (size_t)t * 512, &As[b][wid * 512]);
    gl16(bp + (size_t)t * 512, &Bs[b][wid * 512]);
  };

  stage(0, 0);
  stage(1, 1);
  stage(2, 2);
  asm volatile("s_waitcnt vmcnt(4)" ::: "memory");   // tile 0 landed
  __builtin_amdgcn_s_barrier();

  for (int t = 0; t < KT; ++t) {
    int b = t & 3;
    bf16x8 af[4], bf[2];
#pragma unroll
    for (int mi = 0; mi < 4; mi++)
      af[mi] = *(const bf16x8*)&As[b][(wm * 4 + mi) * 512 + fo];
#pragma unroll
    for (int ni = 0; ni < 2; ni++)
      bf[ni] = *(const bf16x8*)&Bs[b][(wn * 2 + ni) * 512 + fo];
    if (t + 3 < KT) stage((t + 3) & 3, t + 3);
    __builtin_amdgcn_s_setprio(1);
#pragma unroll
    for (int mi = 0; mi < 4; mi++)
#pragma unroll
      for (int ni = 0; ni < 2; ni++)
        acc[mi][ni] = __builtin_amdgcn_mfma_f32_16x16x32_bf16(af[mi], bf[ni], acc[mi][ni], 0, 0, 0);
    __builtin_amdgcn_s_setprio(0);
    if (t + 3 < KT) {
      asm volatile("s_waitcnt vmcnt(4)" ::: "memory");
      __builtin_amdgcn_s_barrier();
    } else if (t + 2 < KT) {
      asm volatile("s_waitcnt vmcnt(2)" ::: "memory");
      __builtin_amdgcn_s_barrier();
    } else if (t + 1 < KT) {
      asm volatile("s_waitcnt vmcnt(0)" ::: "memory");
      __builtin_amdgcn_s_barrier();
    }
  }

  int rbase = m0 + wm * 64;
  int cbase = n0 + wn * 32;
#pragma unroll
  for (int mi = 0; mi < 4; mi++)
#pragma unroll
    for (int ni = 0; ni < 2; ni++) {
      int col = cbase + ni * 16 + fr;
#pragma unroll
      for (int jj = 0; jj < 4; jj++) {
        int row = rbase + mi * 16 + fq * 4 + jj;
        if (row < cnt) {
          float vv = acc[mi][ni][jj];
          if (ROUTED) {
            int tk = toklist[e * T_TOK + row];
            float wgt = wts[e * T_TOK + row];
            atomicAdd(&Out[(size_t)tk * N + col], wgt * vv);
          } else {
            Out[(size_t)row * N + col] = vv;
          }
        }
      }
    }
}

extern "C" void kernel_launch(void* const* d_in, const int* in_sizes, int n_in,
                              void* d_out, int out_size, void* d_ws, size_t ws_size,
                              hipStream_t stream) {
  const float* x = (const float*)d_in[0];
  const int* labels = (const int*)d_in[1];
  const float* cc = (const float*)d_in[2];
  const float* Wg = (const float*)d_in[3];
  const float* Wu = (const float*)d_in[4];
  const float* Wd = (const float*)d_in[5];
  const float* Wgs = (const float*)d_in[6];
  const float* Wus = (const float*)d_in[7];
  const float* Wds = (const float*)d_in[8];
  float* out = (float*)d_out;

  // ---- workspace layout ----
  uint8_t* p = (uint8_t*)d_ws;
  int* counts = (int*)p;            p += 256;
  int* toklist = (int*)p;           p += (size_t)NE * T_TOK * 4;
  float* wts = (float*)p;           p += (size_t)NE * T_TOK * 4;
  unsigned short* xbf = (unsigned short*)p;  p += (size_t)T_TOK * H_DIM * 2;
  unsigned short* WgT = (unsigned short*)p;  p += (size_t)NE * H_DIM * IMOE * 2;
  unsigned short* WuT = (unsigned short*)p;  p += (size_t)NE * H_DIM * IMOE * 2;
  unsigned short* WdT = (unsigned short*)p;  p += (size_t)NE * IMOE * H_DIM * 2;
  unsigned short* WgsT = (unsigned short*)p; p += (size_t)H_DIM * ISHARED * 2;
  unsigned short* WusT = (unsigned short*)p; p += (size_t)H_DIM * ISHARED * 2;
  unsigned short* WdsT = (unsigned short*)p; p += (size_t)ISHARED * H_DIM * 2;
  unsigned short* HhT = (unsigned short*)p;  p += (size_t)NE * T_TOK * IMOE * 2;
  unsigned short* HsT = (unsigned short*)p;  p += (size_t)T_TOK * ISHARED * 2;
  size_t need = (size_t)(p - (uint8_t*)d_ws);
  if (ws_size < need) return;  // fail visibly (harness validates output)

  hipMemsetAsync(d_ws, 0, 64, stream);
  cvt_bf16_kernel<<<(T_TOK * H_DIM / 4 + 255) / 256, 256, 0, stream>>>(x, xbf, T_TOK * H_DIM);
  router_kernel<<<T_TOK / 4, 256, 0, stream>>>(x, labels, cc, counts, toklist, wts);

  transpose_cvt<<<dim3(IMOE / 64, H_DIM / 32, NE), 256, 0, stream>>>(Wg, WgT, H_DIM, IMOE);
  transpose_cvt<<<dim3(IMOE / 64, H_DIM / 32, NE), 256, 0, stream>>>(Wu, WuT, H_DIM, IMOE);
  transpose_cvt<<<dim3(H_DIM / 64, IMOE / 32, NE), 256, 0, stream>>>(Wd, WdT, IMOE, H_DIM);
  transpose_cvt<<<dim3(ISHARED / 64, H_DIM / 32, 1), 256, 0, stream>>>(Wgs, WgsT, H_DIM, ISHARED);
  transpose_cvt<<<dim3(ISHARED / 64, H_DIM / 32, 1), 256, 0, stream>>>(Wus, WusT, H_DIM, ISHARED);
  transpose_cvt<<<dim3(H_DIM / 64, ISHARED / 32, 1), 256, 0, stream>>>(Wds, WdsT, ISHARED, H_DIM);

  gemm_up8<false><<<dim3(ISHARED / 128, T_TOK / 256, 1), 512, 0, stream>>>(
      xbf, WgsT, WusT, HsT, nullptr, nullptr, H_DIM, ISHARED);
  gemm_up8<true><<<dim3(IMOE / 128, T_TOK / 256, NE), 512, 0, stream>>>(
      xbf, WgT, WuT, HhT, toklist, counts, H_DIM, IMOE);

  gemm_down8<false><<<dim3(H_DIM / 128, T_TOK / 128, 1), 512, 0, stream>>>(
      HsT, WdsT, out, nullptr, nullptr, nullptr, ISHARED, H_DIM);
  gemm_down8<true><<<dim3(H_DIM / 128, T_TOK / 128, NE), 512, 0, stream>>>(
      HhT, WdT, out, toklist, wts, counts, IMOE, H_DIM);
}